// Round 4
// baseline (162.904 us; speedup 1.0000x reference)
//
#include <hip/hip_runtime.h>
#include <hip/hip_cooperative_groups.h>
#include <math.h>

#define HID   16
#define BLK   256
#define TBL_N 4096

namespace cg = cooperative_groups;

__device__ __forceinline__ float fast_tanh(float x) {
    float ax = fabsf(x);
    float t  = __expf(-2.0f * ax);                       // in (0,1]
    float r  = (1.0f - t) * __builtin_amdgcn_rcpf(1.0f + t);
    return copysignf(r, x);
}

// full per-pair scalar MLP (phase 1 only: 2*TBL_N+2 evals total per launch)
__device__ __forceinline__ float eta_mlp(float s,
    const float* __restrict__ W1, const float* __restrict__ b1,
    const float* __restrict__ W2, const float* __restrict__ b2,
    const float* __restrict__ W3, const float* __restrict__ b3)
{
    float g[HID];
#pragma unroll
    for (int l = 0; l < HID; ++l) g[l] = fast_tanh(fmaf(s, W1[l], b1[l]));
    float t[HID];
#pragma unroll
    for (int l = 0; l < HID; ++l) t[l] = b2[l];
#pragma unroll
    for (int m = 0; m < HID; ++m) {
        float gm = g[m];
#pragma unroll
        for (int l = 0; l < HID; ++l) t[l] = fmaf(gm, W2[m * HID + l], t[l]);
    }
    float eta = b3[0];
#pragma unroll
    for (int l = 0; l < HID; ++l) eta = fmaf(fast_tanh(t[l]), W3[l], eta);
    return eta;
}

__device__ __forceinline__ void derive_consts(const float* __restrict__ cell,
                                              int n, float* inv_rs, float* smax_s)
{
    const float m00=cell[0],m01=cell[1],m02=cell[2];
    const float m10=cell[3],m11=cell[4],m12=cell[5];
    const float m20=cell[6],m21=cell[7],m22=cell[8];
    const float det = m00*(m11*m22-m12*m21)-m01*(m10*m22-m12*m20)+m02*(m10*m21-m11*m20);
    const float PI = 3.14159265358979323846f;
    const float vol_pp = fabsf(det) / (float)n;
    *inv_rs = cbrtf(4.0f * PI / (3.0f * vol_pp));
    const float r0 = sqrtf(m00*m00+m01*m01+m02*m02);
    const float r1 = sqrtf(m10*m10+m11*m11+m12*m12);
    const float r2 = sqrtf(m20*m20+m21*m21+m22*m22);
    *smax_s = (r0 + r1 + r2) * (1.0f / PI) * (*inv_rs) * 1.0005f;
}

// Single fused cooperative kernel.
// ws: tbl   = float[2*TBL_N + 2]  at d_ws + 0        (P bank, A bank, +1 guard)
//     frac  = float4[n]           at d_ws + 64 KiB   (0.5*frac coords, .w = spin tag)
//     hdr   = float[16]           at d_ws + 128 KiB  (c_u, cell*~(1/pi) rows)
extern "C" __global__ __launch_bounds__(BLK, 4)
void pair_backflow_fused(
    const float* __restrict__ x,   const float* __restrict__ cell,
    const float* __restrict__ Wp1, const float* __restrict__ bp1,
    const float* __restrict__ Wp2, const float* __restrict__ bp2,
    const float* __restrict__ Wp3, const float* __restrict__ bp3,
    const float* __restrict__ Wa1, const float* __restrict__ ba1,
    const float* __restrict__ Wa2, const float* __restrict__ ba2,
    const float* __restrict__ Wa3, const float* __restrict__ ba3,
    const int* __restrict__ n_up_ptr,
    float* __restrict__ tbl, float4* __restrict__ frac, float* __restrict__ hdr,
    float* __restrict__ out, int n)
{
    cg::grid_group gg = cg::this_grid();
    const int tid = threadIdx.x;
    const int g   = blockIdx.x * BLK + tid;

    // ================= phase 1 =================
    if (g <= 2 * TBL_N + 1) {
        // table entries: [0,TBL_N) parallel, [TBL_N,2*TBL_N) anti, +2 guards
        float inv_rs, smax;
        derive_consts(cell, n, &inv_rs, &smax);
        const float ds  = smax / (float)(TBL_N - 1);
        const int bank  = (g >= TBL_N) ? 1 : 0;
        const int gg2   = (g >= 2 * TBL_N) ? (g - TBL_N) : g;  // guards -> past-end idx
        const int idx   = gg2 - bank * TBL_N;
        const float s   = idx * ds;
        float v = bank ? eta_mlp(s, Wa1, ba1, Wa2, ba2, Wa3, ba3)
                       : eta_mlp(s, Wp1, bp1, Wp2, bp2, Wp3, bp3);
        tbl[g] = v;
    } else if (g < 2 * TBL_N + 2 + n) {
        const int i = g - (2 * TBL_N + 2);
        const float m00=cell[0],m01=cell[1],m02=cell[2];
        const float m10=cell[3],m11=cell[4],m12=cell[5];
        const float m20=cell[6],m21=cell[7],m22=cell[8];
        const float det = m00*(m11*m22-m12*m21)-m01*(m10*m22-m12*m20)+m02*(m10*m21-m11*m20);
        const float id  = 1.0f / det;
        const float i00=(m11*m22-m12*m21)*id, i01=(m02*m21-m01*m22)*id, i02=(m01*m12-m02*m11)*id;
        const float i10=(m12*m20-m10*m22)*id, i11=(m00*m22-m02*m20)*id, i12=(m02*m10-m00*m12)*id;
        const float i20=(m10*m21-m11*m20)*id, i21=(m01*m20-m00*m21)*id, i22=(m00*m11-m01*m10)*id;
        const int n_up = *n_up_ptr;
        float x0 = x[i*3+0], x1 = x[i*3+1], x2 = x[i*3+2];
        float4 f;   // pre-scaled by 0.5: v_sin_f32 takes revolutions, sin(pi*d)=sin(2pi*0.5d)
        f.x = 0.5f * (x0*i00 + x1*i10 + x2*i20);
        f.y = 0.5f * (x0*i01 + x1*i11 + x2*i21);
        f.z = 0.5f * (x0*i02 + x1*i12 + x2*i22);
        f.w = (i < n_up) ? 0.0f : 1.0f;   // spin tag
        frac[i] = f;
    } else if (g == 2 * TBL_N + 2 + n) {
        float inv_rs, smax;
        derive_consts(cell, n, &inv_rs, &smax);
        const float IPI = 0.31830988618379067154f;
        hdr[0] = inv_rs * (float)(TBL_N - 1) / smax;   // dist -> table coord
        hdr[1] = cell[0]*IPI; hdr[2] = cell[1]*IPI; hdr[3] = cell[2]*IPI;
        hdr[4] = cell[3]*IPI; hdr[5] = cell[4]*IPI; hdr[6] = cell[5]*IPI;
        hdr[7] = cell[6]*IPI; hdr[8] = cell[7]*IPI; hdr[9] = cell[8]*IPI;
    }

    gg.sync();

    // ================= phase 2: 2 rows per block, shared frac[i] loads ========
    const float c_u  = hdr[0];
    const float c00 = hdr[1], c01 = hdr[2], c02 = hdr[3];
    const float c10 = hdr[4], c11 = hdr[5], c12 = hdr[6];
    const float c20 = hdr[7], c21 = hdr[8], c22 = hdr[9];
    const float umax = (float)(TBL_N - 1);

    const int j0 = blockIdx.x;
    const int j1 = blockIdx.x + (int)gridDim.x;
    const bool has1 = (j1 < n);
    const float4 fj0 = frac[j0];
    const float4 fj1 = has1 ? frac[j1] : fj0;

    float a00 = 0.0f, a01 = 0.0f, a02 = 0.0f;   // dr[j0]
    float a10 = 0.0f, a11 = 0.0f, a12 = 0.0f;   // dr[j1]

    for (int i = tid; i < n; i += BLK) {
        const float4 fi = frac[i];

        // ---- row j0 ----
        {
            float s0 = __builtin_amdgcn_sinf(fi.x - fj0.x);
            float s1 = __builtin_amdgcn_sinf(fi.y - fj0.y);
            float s2 = __builtin_amdgcn_sinf(fi.z - fj0.z);
            float h0 = fmaf(s0, c00, fmaf(s1, c10, s2 * c20));
            float h1 = fmaf(s0, c01, fmaf(s1, c11, s2 * c21));
            float h2 = fmaf(s0, c02, fmaf(s1, c12, s2 * c22));
            float dist = sqrtf(fmaf(h0, h0, fmaf(h1, h1, h2 * h2)));
            float u   = fminf(dist * c_u, umax);
            int   idx = (int)u;
            float fr  = u - (float)idx;
            int   off = (fi.w != fj0.w) ? TBL_N : 0;
            float e0 = tbl[off + idx];
            float e1 = tbl[off + idx + 1];
            float eta = fmaf(fr, e1 - e0, e0);
            a00 = fmaf(-eta, h0, a00);
            a01 = fmaf(-eta, h1, a01);
            a02 = fmaf(-eta, h2, a02);
        }
        // ---- row j1 ----
        {
            float s0 = __builtin_amdgcn_sinf(fi.x - fj1.x);
            float s1 = __builtin_amdgcn_sinf(fi.y - fj1.y);
            float s2 = __builtin_amdgcn_sinf(fi.z - fj1.z);
            float h0 = fmaf(s0, c00, fmaf(s1, c10, s2 * c20));
            float h1 = fmaf(s0, c01, fmaf(s1, c11, s2 * c21));
            float h2 = fmaf(s0, c02, fmaf(s1, c12, s2 * c22));
            float dist = sqrtf(fmaf(h0, h0, fmaf(h1, h1, h2 * h2)));
            float u   = fminf(dist * c_u, umax);
            int   idx = (int)u;
            float fr  = u - (float)idx;
            int   off = (fi.w != fj1.w) ? TBL_N : 0;
            float e0 = tbl[off + idx];
            float e1 = tbl[off + idx + 1];
            float eta = fmaf(fr, e1 - e0, e0);
            a10 = fmaf(-eta, h0, a10);
            a11 = fmaf(-eta, h1, a11);
            a12 = fmaf(-eta, h2, a12);
        }
    }

    // ---- block reduction: butterfly over 64 lanes, then cross-wave LDS ----
#pragma unroll
    for (int off = 32; off > 0; off >>= 1) {
        a00 += __shfl_xor(a00, off); a01 += __shfl_xor(a01, off); a02 += __shfl_xor(a02, off);
        a10 += __shfl_xor(a10, off); a11 += __shfl_xor(a11, off); a12 += __shfl_xor(a12, off);
    }
    __shared__ float sred[BLK / 64][6];
    const int lane = tid & 63;
    const int wid  = tid >> 6;
    if (lane == 0) {
        sred[wid][0] = a00; sred[wid][1] = a01; sred[wid][2] = a02;
        sred[wid][3] = a10; sred[wid][4] = a11; sred[wid][5] = a12;
    }
    __syncthreads();
    if (tid < 6) {
        float dr = 0.0f;
#pragma unroll
        for (int wv = 0; wv < BLK / 64; ++wv) dr += sred[wv][tid];
        const int row  = (tid < 3) ? j0 : j1;
        const int comp = (tid < 3) ? tid : (tid - 3);
        if (tid < 3 || has1)
            out[row * 3 + comp] = x[row * 3 + comp] + dr;
    }
}

extern "C" void kernel_launch(void* const* d_in, const int* in_sizes, int n_in,
                              void* d_out, int out_size, void* d_ws, size_t ws_size,
                              hipStream_t stream) {
    const float* x    = (const float*)d_in[0];
    const float* cell = (const float*)d_in[1];
    const float* Wp1  = (const float*)d_in[2];
    const float* bp1  = (const float*)d_in[3];
    const float* Wp2  = (const float*)d_in[4];
    const float* bp2  = (const float*)d_in[5];
    const float* Wp3  = (const float*)d_in[6];
    const float* bp3  = (const float*)d_in[7];
    const float* Wa1  = (const float*)d_in[8];
    const float* ba1  = (const float*)d_in[9];
    const float* Wa2  = (const float*)d_in[10];
    const float* ba2  = (const float*)d_in[11];
    const float* Wa3  = (const float*)d_in[12];
    const float* ba3  = (const float*)d_in[13];
    const int*   nup  = (const int*)d_in[14];
    float* out = (float*)d_out;

    int n = in_sizes[0] / 3;

    float*  tbl  = (float*)d_ws;                               // 2*TBL_N+2 floats
    float4* frac = (float4*)((char*)d_ws + (64 << 10));        // n float4
    float*  hdr  = (float*)((char*)d_ws + (128 << 10));        // 16 floats

    int gridB = (n + 1) / 2;   // 2 rows per block

    void* args[] = {
        (void*)&x, (void*)&cell,
        (void*)&Wp1, (void*)&bp1, (void*)&Wp2, (void*)&bp2, (void*)&Wp3, (void*)&bp3,
        (void*)&Wa1, (void*)&ba1, (void*)&Wa2, (void*)&ba2, (void*)&Wa3, (void*)&ba3,
        (void*)&nup, (void*)&tbl, (void*)&frac, (void*)&hdr, (void*)&out, (void*)&n
    };
    hipLaunchCooperativeKernel((const void*)pair_backflow_fused,
                               dim3(gridB), dim3(BLK), args, 0, stream);
}

// Round 5
// 92.813 us; speedup vs baseline: 1.7552x; 1.7552x over previous
//
#include <hip/hip_runtime.h>
#include <math.h>

#define HID   16
#define BLK   256
#define TBL_N 4096

__device__ __forceinline__ float fast_tanh(float x) {
    float ax = fabsf(x);
    float t  = __expf(-2.0f * ax);                       // in (0,1]
    float r  = (1.0f - t) * __builtin_amdgcn_rcpf(1.0f + t);
    return copysignf(r, x);
}

// full per-pair scalar MLP (build kernel only: 2*TBL_N+1 evals per launch)
__device__ __forceinline__ float eta_mlp(float s,
    const float* __restrict__ W1, const float* __restrict__ b1,
    const float* __restrict__ W2, const float* __restrict__ b2,
    const float* __restrict__ W3, const float* __restrict__ b3)
{
    float g[HID];
#pragma unroll
    for (int l = 0; l < HID; ++l) g[l] = fast_tanh(fmaf(s, W1[l], b1[l]));
    float t[HID];
#pragma unroll
    for (int l = 0; l < HID; ++l) t[l] = b2[l];
#pragma unroll
    for (int m = 0; m < HID; ++m) {
        float gm = g[m];
#pragma unroll
        for (int l = 0; l < HID; ++l) t[l] = fmaf(gm, W2[m * HID + l], t[l]);
    }
    float eta = b3[0];
#pragma unroll
    for (int l = 0; l < HID; ++l) eta = fmaf(fast_tanh(t[l]), W3[l], eta);
    return eta;
}

// derived constants — identical arithmetic in both kernels
__device__ __forceinline__ void derive_consts(const float* __restrict__ cell,
                                              int n, float* inv_rs, float* smax_s)
{
    const float m00=cell[0],m01=cell[1],m02=cell[2];
    const float m10=cell[3],m11=cell[4],m12=cell[5];
    const float m20=cell[6],m21=cell[7],m22=cell[8];
    const float det = m00*(m11*m22-m12*m21)-m01*(m10*m22-m12*m20)+m02*(m10*m21-m11*m20);
    const float PI = 3.14159265358979323846f;
    const float vol_pp = fabsf(det) / (float)n;
    *inv_rs = cbrtf(4.0f * PI / (3.0f * vol_pp));
    const float r0 = sqrtf(m00*m00+m01*m01+m02*m02);
    const float r1 = sqrtf(m10*m10+m11*m11+m12*m12);
    const float r2 = sqrtf(m20*m20+m21*m21+m22*m22);
    *smax_s = (r0 + r1 + r2) * (1.0f / PI) * (*inv_rs) * 1.0005f;
}

// ws layout: tbl  = float[2*TBL_N + 1]  (P bank, A bank, +1 guard)
//            frac = float4[n] at d_ws + 64 KiB (0.5*frac coords, .w = spin tag)
extern "C" __global__ void build_tables(
    const float* __restrict__ x, const float* __restrict__ cell,
    const float* __restrict__ Wp1, const float* __restrict__ bp1,
    const float* __restrict__ Wp2, const float* __restrict__ bp2,
    const float* __restrict__ Wp3, const float* __restrict__ bp3,
    const float* __restrict__ Wa1, const float* __restrict__ ba1,
    const float* __restrict__ Wa2, const float* __restrict__ ba2,
    const float* __restrict__ Wa3, const float* __restrict__ ba3,
    const int* __restrict__ n_up_ptr,
    float* __restrict__ tbl, float4* __restrict__ frac, int n)
{
    const int t = blockIdx.x * blockDim.x + threadIdx.x;

    if (t <= 2 * TBL_N) {
        // [0,TBL_N) parallel bank, [TBL_N,2*TBL_N) anti bank, [2*TBL_N] guard.
        // Guard is only ever read with weight fr==0 (u clamped to TBL_N-1).
        float inv_rs, smax;
        derive_consts(cell, n, &inv_rs, &smax);
        const float ds  = smax / (float)(TBL_N - 1);
        const int bank  = (t >= TBL_N) ? 1 : 0;
        const int idx   = t - bank * TBL_N;          // guard -> idx=TBL_N (extrapolated)
        const float s   = idx * ds;
        tbl[t] = bank ? eta_mlp(s, Wa1, ba1, Wa2, ba2, Wa3, ba3)
                      : eta_mlp(s, Wp1, bp1, Wp2, bp2, Wp3, bp3);
        return;
    }

    const int i = t - (2 * TBL_N + 1);
    if (i < n) {
        const float m00=cell[0],m01=cell[1],m02=cell[2];
        const float m10=cell[3],m11=cell[4],m12=cell[5];
        const float m20=cell[6],m21=cell[7],m22=cell[8];
        const float det = m00*(m11*m22-m12*m21)-m01*(m10*m22-m12*m20)+m02*(m10*m21-m11*m20);
        const float id  = 1.0f / det;
        const float i00=(m11*m22-m12*m21)*id, i01=(m02*m21-m01*m22)*id, i02=(m01*m12-m02*m11)*id;
        const float i10=(m12*m20-m10*m22)*id, i11=(m00*m22-m02*m20)*id, i12=(m02*m10-m00*m12)*id;
        const float i20=(m10*m21-m11*m20)*id, i21=(m01*m20-m00*m21)*id, i22=(m00*m11-m01*m10)*id;
        const int n_up = *n_up_ptr;
        float x0 = x[i*3+0], x1 = x[i*3+1], x2 = x[i*3+2];
        float4 f;   // pre-scaled by 0.5: v_sin_f32 takes revolutions, sin(pi*d)=sin(2pi*(0.5d))
        f.x = 0.5f * (x0*i00 + x1*i10 + x2*i20);
        f.y = 0.5f * (x0*i01 + x1*i11 + x2*i21);
        f.z = 0.5f * (x0*i02 + x1*i12 + x2*i22);
        f.w = (i < n_up) ? 0.0f : 1.0f;   // spin tag
        frac[i] = f;
    }
}

extern "C" __global__ __launch_bounds__(BLK)
void pair_backflow_main(
    const float* __restrict__ x, const float* __restrict__ cell,
    const float* __restrict__ tbl, const float4* __restrict__ frac,
    float* __restrict__ out, int n)
{
    const int tid = threadIdx.x;

    // wave-uniform constants (recomputed; identical arithmetic to build kernel)
    const float m00=cell[0],m01=cell[1],m02=cell[2];
    const float m10=cell[3],m11=cell[4],m12=cell[5];
    const float m20=cell[6],m21=cell[7],m22=cell[8];
    const float IPI = 0.31830988618379067154f;
    const float c00=m00*IPI, c01=m01*IPI, c02=m02*IPI;
    const float c10=m10*IPI, c11=m11*IPI, c12=m12*IPI;
    const float c20=m20*IPI, c21=m21*IPI, c22=m22*IPI;

    float inv_rs, smax;
    derive_consts(cell, n, &inv_rs, &smax);
    const float c_u  = inv_rs * (float)(TBL_N - 1) / smax;  // dist -> table coord
    const float umax = (float)(TBL_N - 1);

    // two rows per block, sharing each frac[i] load
    const int j0 = blockIdx.x;
    const int j1 = blockIdx.x + (int)gridDim.x;
    const bool has1 = (j1 < n);
    const float4 fj0 = frac[j0];
    const float4 fj1 = has1 ? frac[j1] : fj0;

    float a00 = 0.0f, a01 = 0.0f, a02 = 0.0f;   // dr[j0]
    float a10 = 0.0f, a11 = 0.0f, a12 = 0.0f;   // dr[j1]

#pragma unroll 3
    for (int i = tid; i < n; i += BLK) {
        const float4 fi = frac[i];
        {
            float s0 = __builtin_amdgcn_sinf(fi.x - fj0.x);
            float s1 = __builtin_amdgcn_sinf(fi.y - fj0.y);
            float s2 = __builtin_amdgcn_sinf(fi.z - fj0.z);
            float h0 = fmaf(s0, c00, fmaf(s1, c10, s2 * c20));
            float h1 = fmaf(s0, c01, fmaf(s1, c11, s2 * c21));
            float h2 = fmaf(s0, c02, fmaf(s1, c12, s2 * c22));
            float dist = sqrtf(fmaf(h0, h0, fmaf(h1, h1, h2 * h2)));
            float u   = fminf(dist * c_u, umax);
            int   idx = (int)u;
            float fr  = u - (float)idx;
            int   off = (fi.w != fj0.w) ? TBL_N : 0;
            float e0 = tbl[off + idx];
            float e1 = tbl[off + idx + 1];
            float eta = fmaf(fr, e1 - e0, e0);   // diagonal: h==0 contributes 0
            a00 = fmaf(-eta, h0, a00);
            a01 = fmaf(-eta, h1, a01);
            a02 = fmaf(-eta, h2, a02);
        }
        {
            float s0 = __builtin_amdgcn_sinf(fi.x - fj1.x);
            float s1 = __builtin_amdgcn_sinf(fi.y - fj1.y);
            float s2 = __builtin_amdgcn_sinf(fi.z - fj1.z);
            float h0 = fmaf(s0, c00, fmaf(s1, c10, s2 * c20));
            float h1 = fmaf(s0, c01, fmaf(s1, c11, s2 * c21));
            float h2 = fmaf(s0, c02, fmaf(s1, c12, s2 * c22));
            float dist = sqrtf(fmaf(h0, h0, fmaf(h1, h1, h2 * h2)));
            float u   = fminf(dist * c_u, umax);
            int   idx = (int)u;
            float fr  = u - (float)idx;
            int   off = (fi.w != fj1.w) ? TBL_N : 0;
            float e0 = tbl[off + idx];
            float e1 = tbl[off + idx + 1];
            float eta = fmaf(fr, e1 - e0, e0);
            a10 = fmaf(-eta, h0, a10);
            a11 = fmaf(-eta, h1, a11);
            a12 = fmaf(-eta, h2, a12);
        }
    }

    // block reduction: 64-lane butterfly, then cross-wave via LDS
#pragma unroll
    for (int off = 32; off > 0; off >>= 1) {
        a00 += __shfl_xor(a00, off); a01 += __shfl_xor(a01, off); a02 += __shfl_xor(a02, off);
        a10 += __shfl_xor(a10, off); a11 += __shfl_xor(a11, off); a12 += __shfl_xor(a12, off);
    }
    __shared__ float sred[BLK / 64][6];
    const int lane = tid & 63;
    const int wid  = tid >> 6;
    if (lane == 0) {
        sred[wid][0] = a00; sred[wid][1] = a01; sred[wid][2] = a02;
        sred[wid][3] = a10; sred[wid][4] = a11; sred[wid][5] = a12;
    }
    __syncthreads();
    if (tid < 6) {
        float dr = 0.0f;
#pragma unroll
        for (int wv = 0; wv < BLK / 64; ++wv) dr += sred[wv][tid];
        const int row  = (tid < 3) ? j0 : j1;
        const int comp = (tid < 3) ? tid : (tid - 3);
        if (tid < 3 || has1)
            out[row * 3 + comp] = x[row * 3 + comp] + dr;
    }
}

extern "C" void kernel_launch(void* const* d_in, const int* in_sizes, int n_in,
                              void* d_out, int out_size, void* d_ws, size_t ws_size,
                              hipStream_t stream) {
    const float* x    = (const float*)d_in[0];
    const float* cell = (const float*)d_in[1];
    const float* Wp1  = (const float*)d_in[2];
    const float* bp1  = (const float*)d_in[3];
    const float* Wp2  = (const float*)d_in[4];
    const float* bp2  = (const float*)d_in[5];
    const float* Wp3  = (const float*)d_in[6];
    const float* bp3  = (const float*)d_in[7];
    const float* Wa1  = (const float*)d_in[8];
    const float* ba1  = (const float*)d_in[9];
    const float* Wa2  = (const float*)d_in[10];
    const float* ba2  = (const float*)d_in[11];
    const float* Wa3  = (const float*)d_in[12];
    const float* ba3  = (const float*)d_in[13];
    const int*   nup  = (const int*)d_in[14];
    float* out = (float*)d_out;

    const int n = in_sizes[0] / 3;

    float*  tbl  = (float*)d_ws;                          // 2*TBL_N+1 floats
    float4* frac = (float4*)((char*)d_ws + (64 << 10));   // n float4

    const int work = 2 * TBL_N + 1 + n;
    build_tables<<<dim3((work + BLK - 1) / BLK), dim3(BLK), 0, stream>>>(
        x, cell, Wp1, bp1, Wp2, bp2, Wp3, bp3,
        Wa1, ba1, Wa2, ba2, Wa3, ba3, nup, tbl, frac, n);

    const int gridB = (n + 1) / 2;   // 2 rows per block
    pair_backflow_main<<<dim3(gridB), dim3(BLK), 0, stream>>>(
        x, cell, tbl, frac, out, n);
}